// Round 1
// baseline (74.455 us; speedup 1.0000x reference)
//
#include <hip/hip_runtime.h>
#include <math.h>

#define N_PTS 262144
#define WIDTH 256

__device__ __forceinline__ void jrot(double &app, double &aqq, double &apq,
                                     double &arp, double &arq,
                                     double &vp0, double &vq0,
                                     double &vp1, double &vq1,
                                     double &vp2, double &vq2)
{
    double a = apq;
    if (fabs(a) < 1e-300) return;
    double theta = (aqq - app) / (2.0 * a);
    double tt = copysign(1.0, theta) / (fabs(theta) + sqrt(1.0 + theta * theta));
    double c = 1.0 / sqrt(1.0 + tt * tt);
    double s = tt * c;
    app -= tt * a;
    aqq += tt * a;
    apq = 0.0;
    double rp = arp, rq = arq;
    arp = c * rp - s * rq;
    arq = s * rp + c * rq;
    double t0p = vp0, t0q = vq0; vp0 = c * t0p - s * t0q; vq0 = s * t0p + c * t0q;
    double t1p = vp1, t1q = vq1; vp1 = c * t1p - s * t1q; vq1 = s * t1p + c * t1q;
    double t2p = vp2, t2q = vq2; vp2 = c * t2p - s * t2q; vq2 = s * t2p + c * t2q;
}

__global__ __launch_bounds__(256) void so3_kernel(
    const float* __restrict__ x,
    const float* __restrict__ fw,
    const float* __restrict__ fb,
    float* __restrict__ out)
{
    __shared__ float xs[256][33];   // +1 pad: read bank = (t+kk)%32, conflict-free
    const int t  = threadIdx.x;
    const int p0 = blockIdx.x << 8;

    float y[9];
#pragma unroll
    for (int j = 0; j < 9; ++j) y[j] = 0.f;

    for (int kc = 0; kc < 8; ++kc) {
        const int k0 = kc << 5;
        // stage 256 pts x 32 cols, coalesced float4 (8 threads per row-segment)
#pragma unroll
        for (int i = 0; i < 8; ++i) {
            const int flat = (i << 8) + t;      // float4 index 0..2047
            const int row  = flat >> 3;
            const int c4   = flat & 7;
            const float4 v = *reinterpret_cast<const float4*>(
                x + (size_t)(p0 + row) * WIDTH + k0 + (c4 << 2));
            xs[row][(c4 << 2) + 0] = v.x;
            xs[row][(c4 << 2) + 1] = v.y;
            xs[row][(c4 << 2) + 2] = v.z;
            xs[row][(c4 << 2) + 3] = v.w;
        }
        __syncthreads();
#pragma unroll
        for (int kk = 0; kk < 32; ++kk) {
            const float xv = xs[t][kk];
            const int k = k0 + kk;              // uniform -> scalar loads of fw
#pragma unroll
            for (int j = 0; j < 9; ++j)
                y[j] = fmaf(xv, fw[j * WIDTH + k], y[j]);
        }
        __syncthreads();
    }
#pragma unroll
    for (int j = 0; j < 9; ++j) y[j] += fb[j];

    // ---- fp64 3x3 symmetric orthogonalization (special Procrustes) ----
    const double m00 = y[0], m01 = y[1], m02 = y[2];
    const double m10 = y[3], m11 = y[4], m12 = y[5];
    const double m20 = y[6], m21 = y[7], m22 = y[8];

    // A = M^T M (symmetric)
    double a00 = m00*m00 + m10*m10 + m20*m20;
    double a01 = m00*m01 + m10*m11 + m20*m21;
    double a02 = m00*m02 + m10*m12 + m20*m22;
    double a11 = m01*m01 + m11*m11 + m21*m21;
    double a12 = m01*m02 + m11*m12 + m21*m22;
    double a22 = m02*m02 + m12*m12 + m22*m22;

    double v[3][3] = { {1,0,0}, {0,1,0}, {0,0,1} };   // columns = eigenvectors

#pragma unroll
    for (int sw = 0; sw < 4; ++sw) {
        jrot(a00, a11, a01, a02, a12,
             v[0][0], v[0][1], v[1][0], v[1][1], v[2][0], v[2][1]);   // (p,q)=(0,1)
        jrot(a00, a22, a02, a01, a12,
             v[0][0], v[0][2], v[1][0], v[1][2], v[2][0], v[2][2]);   // (p,q)=(0,2)
        jrot(a11, a22, a12, a01, a02,
             v[0][1], v[0][2], v[1][1], v[1][2], v[2][1], v[2][2]);   // (p,q)=(1,2)
    }

    // sort eigenvalues descending, swap eigenvector columns along
    double d0 = a00, d1 = a11, d2 = a22, tmp;
    if (d0 < d1) { tmp=d0; d0=d1; d1=tmp;
        tmp=v[0][0]; v[0][0]=v[0][1]; v[0][1]=tmp;
        tmp=v[1][0]; v[1][0]=v[1][1]; v[1][1]=tmp;
        tmp=v[2][0]; v[2][0]=v[2][1]; v[2][1]=tmp; }
    if (d0 < d2) { tmp=d0; d0=d2; d2=tmp;
        tmp=v[0][0]; v[0][0]=v[0][2]; v[0][2]=tmp;
        tmp=v[1][0]; v[1][0]=v[1][2]; v[1][2]=tmp;
        tmp=v[2][0]; v[2][0]=v[2][2]; v[2][2]=tmp; }
    if (d1 < d2) { tmp=d1; d1=d2; d2=tmp;
        tmp=v[0][1]; v[0][1]=v[0][2]; v[0][2]=tmp;
        tmp=v[1][1]; v[1][1]=v[1][2]; v[1][2]=tmp;
        tmp=v[2][1]; v[2][1]=v[2][2]; v[2][2]=tmp; }

    const double v1x = v[0][0], v1y = v[1][0], v1z = v[2][0];
    const double v2x = v[0][1], v2y = v[1][1], v2z = v[2][1];

    // u1 = normalize(M v1)
    double u1x = m00*v1x + m01*v1y + m02*v1z;
    double u1y = m10*v1x + m11*v1y + m12*v1z;
    double u1z = m20*v1x + m21*v1y + m22*v1z;
    double inv1 = 1.0 / (sqrt(u1x*u1x + u1y*u1y + u1z*u1z) + 1e-300);
    u1x *= inv1; u1y *= inv1; u1z *= inv1;

    // u2 = normalize(M v2 - (u1 . M v2) u1)
    double u2x = m00*v2x + m01*v2y + m02*v2z;
    double u2y = m10*v2x + m11*v2y + m12*v2z;
    double u2z = m20*v2x + m21*v2y + m22*v2z;
    const double d12 = u1x*u2x + u1y*u2y + u1z*u2z;
    u2x -= d12*u1x; u2y -= d12*u1y; u2z -= d12*u1z;
    double inv2 = 1.0 / (sqrt(u2x*u2x + u2y*u2y + u2z*u2z) + 1e-300);
    u2x *= inv2; u2y *= inv2; u2z *= inv2;

    // u3 = u1 x u2 ; v3 = v1 x v2 (right-handed bases)
    const double u3x = u1y*u2z - u1z*u2y;
    const double u3y = u1z*u2x - u1x*u2z;
    const double u3z = u1x*u2y - u1y*u2x;
    const double v3x = v1y*v2z - v1z*v2y;
    const double v3y = v1z*v2x - v1x*v2z;
    const double v3z = v1x*v2y - v1y*v2x;

    // R = u1 v1^T + u2 v2^T + u3 v3^T
    float r[9];
    r[0] = (float)(u1x*v1x + u2x*v2x + u3x*v3x);
    r[1] = (float)(u1x*v1y + u2x*v2y + u3x*v3y);
    r[2] = (float)(u1x*v1z + u2x*v2z + u3x*v3z);
    r[3] = (float)(u1y*v1x + u2y*v2x + u3y*v3x);
    r[4] = (float)(u1y*v1y + u2y*v2y + u3y*v3y);
    r[5] = (float)(u1y*v1z + u2y*v2z + u3y*v3z);
    r[6] = (float)(u1z*v1x + u2z*v2x + u3z*v3x);
    r[7] = (float)(u1z*v1y + u2z*v2y + u3z*v3y);
    r[8] = (float)(u1z*v1z + u2z*v2z + u3z*v3z);

    float* o = out + (size_t)(p0 + t) * 9;
#pragma unroll
    for (int j = 0; j < 9; ++j) o[j] = r[j];
}

extern "C" void kernel_launch(void* const* d_in, const int* in_sizes, int n_in,
                              void* d_out, int out_size, void* d_ws, size_t ws_size,
                              hipStream_t stream) {
    const float* x  = (const float*)d_in[0];
    const float* fw = (const float*)d_in[1];
    const float* fb = (const float*)d_in[2];
    float* out = (float*)d_out;
    dim3 grid(N_PTS / 256), block(256);
    hipLaunchKernelGGL(so3_kernel, grid, block, 0, stream, x, fw, fb, out);
}